// Round 5
// baseline (604.152 us; speedup 1.0000x reference)
//
#include <hip/hip_runtime.h>
#include <math.h>

#define HH 128
#define BB 2
#define NN 48
#define TT 24
#define MM 192
#define LL 20
#define NT (BB*NN*TT)   /* 2304 */
#define RSQRT_H 0.08838834764831845f  /* 1/sqrt(128) */
#define RADIUS_C 30.0f
#define NBLK 512

struct P {
    const float *astate, *amask, *polylines, *poly_mask;
    const int *ptype, *tlst, *route;
    const float *ae_w0,*ae_b0,*ae_w1,*ae_b1,*ae_w2,*ae_b2;
    const float *mp_w0,*mp_b0,*mp_w1,*mp_b1;
    const float *type_emb,*tl_emb,*route_emb;
    const float *mo_w0,*mo_b0,*mo_w1,*mo_b1;
    const float *mr_w0,*mr_b0,*mr_w1,*mr_b1;
    const float *nr_w0,*nr_b0,*nr_w1,*nr_b1;
    const float *to_w0,*to_b0,*to_w1,*to_b1;
    float *tau,*map_ctx,*nbr_ctx;
    float *a_emb,*map_node,*map_nodeT,*map_center;
    unsigned *bar;
};

// ---- per-phase LDS layouts (plain float arrays; union via raw buffer) ----
struct SME { float pts[LL*2]; float h1[LL][HH]; float mx[2][HH]; float hb[HH]; float pr[2][HH]; float hb2[HH]; };
struct SAG { float xin[4][5]; float h1[4][HH]; float h2[4][HH]; float p1[2][4][HH]; };
struct SMA { float mnL[16][MM]; float w4L[HH][4]; float w1L[HH]; float aq4L[HH][4]; float lg[4][MM]; float p4L[MM][4]; float invL[4]; float pc[2][4][HH]; };
struct SNB { float aVL[NN][129]; float pjL[NN][8]; float wAL[HH][4]; float wBL[HH][4]; float aqL[HH][8]; float sPL[4][6][NN]; float dPL[4][6][NN]; float lgL[6][NN]; float pL[NN][8]; float pcL[2][6][HH]; };
struct STA { float xinT[3*HH][4]; float p1L[2][4][HH]; float h1T[HH][4]; };

// ---- device-scope one-shot grid barrier ----
__device__ __forceinline__ void grid_barrier(unsigned* bar, int which, unsigned nb) {
    __syncthreads();
    if (threadIdx.x == 0) {
        __threadfence();   // release: make this block's writes device-visible
        unsigned* cnt = bar + which*32;
        unsigned* flg = bar + which*32 + 16;
        unsigned v = __hip_atomic_fetch_add(cnt, 1u, __ATOMIC_ACQ_REL, __HIP_MEMORY_SCOPE_AGENT);
        if (v == nb - 1u) {
            __hip_atomic_store(flg, 1u, __ATOMIC_RELEASE, __HIP_MEMORY_SCOPE_AGENT);
        } else {
            while (__hip_atomic_load(flg, __ATOMIC_ACQUIRE, __HIP_MEMORY_SCOPE_AGENT) == 0u) {
                __builtin_amdgcn_s_sleep(8);
            }
        }
        __threadfence();   // acquire: invalidate stale cached lines
    }
    __syncthreads();
}

// ---------------- phase 1a: map polyline encoder (one bm per task) ----------------
__device__ void do_map_enc(const P& p, SME& s, int bm) {
    int tid = threadIdx.x, pp = tid >> 7, c = tid & 127;
    __syncthreads();
    if (tid < LL*2) s.pts[tid] = p.polylines[(size_t)bm*LL*2 + tid];
    __syncthreads();
    {
        float w0x = p.mp_w0[c], w0y = p.mp_w0[HH + c], b0 = p.mp_b0[c];
        #pragma unroll
        for (int i = 0; i < 10; ++i) {
            int pt_ = pp + 2*i;
            s.h1[pt_][c] = fmaxf(fmaf(s.pts[2*pt_], w0x, fmaf(s.pts[2*pt_+1], w0y, b0)), 0.f);
        }
    }
    if (tid < 2) {
        float sum = 0.f;
        for (int q = 0; q < LL; ++q) sum += s.pts[2*q + tid];
        p.map_center[bm*2 + tid] = sum * (1.0f / LL);
    }
    __syncthreads();
    {
        float acc[10];
        float b1 = p.mp_b1[c];
        #pragma unroll
        for (int i = 0; i < 10; ++i) acc[i] = b1;
        for (int k = 0; k < HH; ++k) {
            float wv = p.mp_w1[k*HH + c];
            #pragma unroll
            for (int i = 0; i < 10; ++i) acc[i] = fmaf(s.h1[pp + 2*i][k], wv, acc[i]);
        }
        float m10 = acc[0];
        #pragma unroll
        for (int i = 1; i < 10; ++i) m10 = fmaxf(m10, acc[i]);
        s.mx[pp][c] = m10;
    }
    __syncthreads();
    if (tid < HH) {
        float hm = fmaxf(fmaxf(s.mx[0][c], s.mx[1][c]), 0.f);
        int pt = p.ptype[bm]; pt = pt < 0 ? 0 : (pt > 3 ? 3 : pt);
        int tv = p.tlst[bm];  tv = tv < 0 ? 0 : (tv > 7 ? 7 : tv);
        int rv = p.route[bm]; rv = rv < 0 ? 0 : (rv > 1 ? 1 : rv);
        hm += p.type_emb[pt*HH + c] + p.tl_emb[tv*HH + c] + p.route_emb[rv*HH + c];
        s.hb[c] = hm;
    }
    __syncthreads();
    {
        float sum = 0.f;
        int k0 = pp*64;
        for (int k = k0; k < k0 + 64; ++k) sum = fmaf(s.hb[k], p.mo_w0[k*HH + c], sum);
        s.pr[pp][c] = sum;
    }
    __syncthreads();
    if (tid < HH) s.hb2[c] = fmaxf(s.pr[0][c] + s.pr[1][c] + p.mo_b0[c], 0.f);
    __syncthreads();
    {
        float sum = 0.f;
        int k0 = pp*64;
        for (int k = k0; k < k0 + 64; ++k) sum = fmaf(s.hb2[k], p.mo_w1[k*HH + c], sum);
        s.pr[pp][c] = sum;
    }
    __syncthreads();
    if (tid < HH) {
        float a3 = s.pr[0][c] + s.pr[1][c] + p.mo_b1[c];
        float mk = (p.poly_mask[bm] > 0.5f) ? 1.f : 0.f;
        float v = a3 * mk;
        p.map_node[(size_t)bm*HH + c] = v;
        int b = bm / MM, m = bm % MM;
        p.map_nodeT[((size_t)b*HH + c)*MM + m] = v;
    }
}

// ---------------- phase 1b: agent encoder (4 rows per task) ----------------
__device__ void do_agent_enc(const P& p, SAG& s, int r0) {
    int tid = threadIdx.x, h = tid >> 7, c = tid & 127;
    __syncthreads();
    if (tid < 20) s.xin[tid/5][tid%5] = p.astate[(size_t)r0*5 + tid];
    __syncthreads();
    if (h == 0) {
        float b = p.ae_b0[c];
        float w[5];
        #pragma unroll
        for (int i = 0; i < 5; ++i) w[i] = p.ae_w0[i*HH + c];
        #pragma unroll
        for (int r = 0; r < 4; ++r) {
            float v = b;
            #pragma unroll
            for (int i = 0; i < 5; ++i) v = fmaf(s.xin[r][i], w[i], v);
            s.h1[r][c] = fmaxf(v, 0.f);
        }
    }
    __syncthreads();
    {
        float acc[4] = {0.f,0.f,0.f,0.f};
        int k0 = h*64;
        for (int k = k0; k < k0 + 64; ++k) {
            float wv = p.ae_w1[k*HH + c];
            #pragma unroll
            for (int r = 0; r < 4; ++r) acc[r] = fmaf(s.h1[r][k], wv, acc[r]);
        }
        #pragma unroll
        for (int r = 0; r < 4; ++r) s.p1[h][r][c] = acc[r];
    }
    __syncthreads();
    {
        #pragma unroll
        for (int rr = 0; rr < 2; ++rr) {
            int r = h*2 + rr;
            s.h2[r][c] = fmaxf(s.p1[0][r][c] + s.p1[1][r][c] + p.ae_b1[c], 0.f);
        }
    }
    __syncthreads();
    {
        float acc[4] = {0.f,0.f,0.f,0.f};
        int k0 = h*64;
        for (int k = k0; k < k0 + 64; ++k) {
            float wv = p.ae_w2[k*HH + c];
            #pragma unroll
            for (int r = 0; r < 4; ++r) acc[r] = fmaf(s.h2[r][k], wv, acc[r]);
        }
        #pragma unroll
        for (int r = 0; r < 4; ++r) s.p1[h][r][c] = acc[r];
    }
    __syncthreads();
    {
        #pragma unroll
        for (int rr = 0; rr < 2; ++rr) {
            int r = h*2 + rr;
            int row = r0 + r;
            p.a_emb[(size_t)row*HH + c] = (s.p1[0][r][c] + s.p1[1][r][c] + p.ae_b2[c]) * p.amask[row];
        }
    }
}

// ---------------- phase 2a: map cross-attention (4 rows per task) ----------------
__device__ void do_map_attn(const P& p, SMA& s, int bnt0) {
    int b   = bnt0 / (NN*TT);
    int tid = threadIdx.x;
    __syncthreads();

    if (tid < HH) {
        int k = tid;
        s.w4L[k][0] = p.mr_w0[k];      s.w4L[k][1] = p.mr_w0[HH+k];
        s.w4L[k][2] = p.mr_w0[2*HH+k]; s.w4L[k][3] = p.mr_b0[k];
        s.w1L[k]    = p.mr_w1[k];
    }
    for (int idx = tid; idx < 4*HH; idx += 256) {
        int r = idx >> 7, k = idx & 127;
        s.aq4L[k][r] = p.a_emb[(size_t)(bnt0 + r)*HH + k];
    }

    float rx[4], ry[4], rd[4];
    if (tid < MM) {
        float mcx = p.map_center[(b*MM + tid)*2];
        float mcy = p.map_center[(b*MM + tid)*2 + 1];
        #pragma unroll
        for (int r = 0; r < 4; ++r) {
            float px = p.astate[(size_t)(bnt0 + r)*5];
            float py = p.astate[(size_t)(bnt0 + r)*5 + 1];
            rx[r] = mcx - px; ry[r] = mcy - py;
            rd[r] = sqrtf(rx[r]*rx[r] + ry[r]*ry[r]);
        }
    }

    const float* mnT = p.map_nodeT + (size_t)b*HH*MM;
    float4 st[3];
    #pragma unroll
    for (int i = 0; i < 3; ++i) {
        int q = tid + 256*i;
        int kk = q / 48, mq = q % 48;
        st[i] = *(const float4*)(mnT + (size_t)kk*MM + mq*4);
    }
    float sacc[4] = {0.f,0.f,0.f,0.f};
    float dt[4]   = {0.f,0.f,0.f,0.f};
    for (int ch = 0; ch < 8; ++ch) {
        __syncthreads();
        #pragma unroll
        for (int i = 0; i < 3; ++i) {
            int q = tid + 256*i;
            int kk = q / 48, mq = q % 48;
            *(float4*)&s.mnL[kk][mq*4] = st[i];
        }
        __syncthreads();
        if (ch < 7) {
            #pragma unroll
            for (int i = 0; i < 3; ++i) {
                int q = tid + 256*i;
                int kk = q / 48, mq = q % 48;
                st[i] = *(const float4*)(mnT + (size_t)(ch+1)*16*MM + (size_t)kk*MM + mq*4);
            }
        }
        if (tid < MM) {
            int k0 = ch*16;
            #pragma unroll
            for (int kk = 0; kk < 16; ++kk) {
                int k = k0 + kk;
                float wx = s.w4L[k][0], wy = s.w4L[k][1], wz = s.w4L[k][2], wb = s.w4L[k][3];
                float w1 = s.w1L[k];
                float mn = s.mnL[kk][tid];
                #pragma unroll
                for (int r = 0; r < 4; ++r) {
                    float hv = fmaf(rx[r], wx, fmaf(ry[r], wy, fmaf(rd[r], wz, wb)));
                    sacc[r] = fmaf(fmaxf(hv, 0.f), w1, sacc[r]);
                }
                dt[0] = fmaf(s.aq4L[k][0], mn, dt[0]);
                dt[1] = fmaf(s.aq4L[k][1], mn, dt[1]);
                dt[2] = fmaf(s.aq4L[k][2], mn, dt[2]);
                dt[3] = fmaf(s.aq4L[k][3], mn, dt[3]);
            }
        }
    }

    if (tid < MM) {
        float pm = p.poly_mask[b*MM + tid];
        float b1 = p.mr_b1[0];
        #pragma unroll
        for (int r = 0; r < 4; ++r) {
            float lgt = fmaf(dt[r], RSQRT_H, sacc[r] + b1);
            s.lg[r][tid] = (pm > 0.5f) ? lgt : -1e9f;
        }
    }
    __syncthreads();

    {
        int r = tid >> 6, l = tid & 63;
        float v = fmaxf(fmaxf(s.lg[r][l], s.lg[r][l+64]), s.lg[r][l+128]);
        #pragma unroll
        for (int o = 32; o > 0; o >>= 1) v = fmaxf(v, __shfl_xor(v, o));
        float e0 = expf(s.lg[r][l] - v);
        float e1 = expf(s.lg[r][l+64] - v);
        float e2 = expf(s.lg[r][l+128] - v);
        s.lg[r][l] = e0; s.lg[r][l+64] = e1; s.lg[r][l+128] = e2;
        float sm = e0 + e1 + e2;
        #pragma unroll
        for (int o = 32; o > 0; o >>= 1) sm += __shfl_xor(sm, o);
        if (l == 0) s.invL[r] = 1.0f / sm;
    }
    __syncthreads();
    if (tid < MM) {
        s.p4L[tid][0] = s.lg[0][tid]*s.invL[0];
        s.p4L[tid][1] = s.lg[1][tid]*s.invL[1];
        s.p4L[tid][2] = s.lg[2][tid]*s.invL[2];
        s.p4L[tid][3] = s.lg[3][tid]*s.invL[3];
    }
    __syncthreads();

    {
        int half = tid >> 7, c = tid & 127;
        float a0=0.f, a1=0.f, a2=0.f, a3=0.f;
        const float* mnb = p.map_node + ((size_t)b*MM + half*96)*HH + c;
        for (int m = 0; m < 96; ++m) {
            float mv = mnb[(size_t)m*HH];
            float4 pp4 = *(const float4*)&s.p4L[half*96 + m][0];
            a0 = fmaf(pp4.x, mv, a0); a1 = fmaf(pp4.y, mv, a1);
            a2 = fmaf(pp4.z, mv, a2); a3 = fmaf(pp4.w, mv, a3);
        }
        s.pc[half][0][c]=a0; s.pc[half][1][c]=a1; s.pc[half][2][c]=a2; s.pc[half][3][c]=a3;
    }
    __syncthreads();
    for (int idx = tid; idx < 4*HH; idx += 256) {
        int r = idx >> 7, c = idx & 127;
        p.map_ctx[(size_t)(bnt0 + r)*HH + c] = s.pc[0][r][c] + s.pc[1][r][c];
    }
}

// ---------------- phase 2b: neighbor attention (6 n-rows per task) ----------------
__device__ void do_nbr_attn(const P& p, SNB& s, int task) {
    int b   = task / (TT*8);
    int rem = task % (TT*8);
    int t   = rem / 8;
    int n0  = (rem % 8) * 6;
    int tid = threadIdx.x;
    __syncthreads();

    if (tid < NN) {
        int rj = (b*NN + tid)*TT + t;
        s.pjL[tid][0] = p.astate[(size_t)rj*5];
        s.pjL[tid][1] = p.astate[(size_t)rj*5 + 1];
        s.pjL[tid][2] = p.astate[(size_t)rj*5 + 3];
        s.pjL[tid][3] = p.astate[(size_t)rj*5 + 4];
        s.pjL[tid][4] = p.amask[rj];
    }
    if (tid < HH) {
        int k = tid;
        s.wAL[k][0] = p.nr_w0[k];      s.wAL[k][1] = p.nr_w0[HH+k];
        s.wAL[k][2] = p.nr_w0[2*HH+k]; s.wAL[k][3] = p.nr_w0[3*HH+k];
        s.wBL[k][0] = p.nr_w0[4*HH+k]; s.wBL[k][1] = p.nr_b0[k];
        s.wBL[k][2] = p.nr_w1[k];      s.wBL[k][3] = 0.f;
    }
    #pragma unroll
    for (int i = 0; i < 6; ++i) {
        int q = tid + 256*i;
        int j = q >> 5, cq = q & 31;
        float4 v = *(const float4*)(p.a_emb + ((size_t)(b*NN + j)*TT + t)*HH + cq*4);
        s.aVL[j][cq*4+0] = v.x; s.aVL[j][cq*4+1] = v.y;
        s.aVL[j][cq*4+2] = v.z; s.aVL[j][cq*4+3] = v.w;
    }
    __syncthreads();
    for (int idx = tid; idx < 6*HH; idx += 256) {
        int r = idx >> 7, k = idx & 127;
        s.aqL[k][r] = s.aVL[n0 + r][k];
    }
    __syncthreads();

    {
        int j  = tid % 48;
        int kg = tid / 48;
        if (kg < 4) {
            float jx = s.pjL[j][0], jy = s.pjL[j][1], jvx = s.pjL[j][2], jvy = s.pjL[j][3];
            float dx[6], dy[6], dvx[6], dvy[6], dd[6];
            #pragma unroll
            for (int r = 0; r < 6; ++r) {
                dx[r]  = s.pjL[n0+r][0] - jx;  dy[r]  = s.pjL[n0+r][1] - jy;
                dvx[r] = s.pjL[n0+r][2] - jvx; dvy[r] = s.pjL[n0+r][3] - jvy;
                dd[r]  = sqrtf(dx[r]*dx[r] + dy[r]*dy[r]);
            }
            float sr[6]  = {0,0,0,0,0,0};
            float dt[6] = {0,0,0,0,0,0};
            int k0 = kg*32;
            for (int kk = 0; kk < 32; ++kk) {
                int k = k0 + kk;
                float wax = s.wAL[k][0], way = s.wAL[k][1], waz = s.wAL[k][2], waw = s.wAL[k][3];
                float wbx = s.wBL[k][0], wby = s.wBL[k][1], wbz = s.wBL[k][2];
                float4 aA = *(const float4*)&s.aqL[k][0];
                float4 aB = *(const float4*)&s.aqL[k][4];
                float  av = s.aVL[j][k];
                #pragma unroll
                for (int r = 0; r < 6; ++r) {
                    float hv = fmaf(dx[r], wax, fmaf(dy[r], way,
                               fmaf(dvx[r], waz, fmaf(dvy[r], waw,
                               fmaf(dd[r], wbx, wby)))));
                    sr[r] = fmaf(fmaxf(hv, 0.f), wbz, sr[r]);
                }
                dt[0] = fmaf(aA.x, av, dt[0]); dt[1] = fmaf(aA.y, av, dt[1]);
                dt[2] = fmaf(aA.z, av, dt[2]); dt[3] = fmaf(aA.w, av, dt[3]);
                dt[4] = fmaf(aB.x, av, dt[4]); dt[5] = fmaf(aB.y, av, dt[5]);
            }
            #pragma unroll
            for (int r = 0; r < 6; ++r) { s.sPL[kg][r][j] = sr[r]; s.dPL[kg][r][j] = dt[r]; }
        }
    }
    __syncthreads();

    float b1 = p.nr_b1[0];
    for (int idx = tid; idx < 6*NN; idx += 256) {
        int r = idx / NN, jj = idx % NN;
        int ni = n0 + r;
        float ss  = s.sPL[0][r][jj] + s.sPL[1][r][jj] + s.sPL[2][r][jj] + s.sPL[3][r][jj] + b1;
        float do2 = s.dPL[0][r][jj] + s.dPL[1][r][jj] + s.dPL[2][r][jj] + s.dPL[3][r][jj];
        float ddx = s.pjL[ni][0] - s.pjL[jj][0];
        float ddy = s.pjL[ni][1] - s.pjL[jj][1];
        float dist = sqrtf(ddx*ddx + ddy*ddy);
        bool ok = (s.pjL[ni][4] > 0.5f) && (s.pjL[jj][4] > 0.5f) &&
                  (dist <= RADIUS_C) && (jj != ni);
        s.lgL[r][jj] = ok ? fmaf(do2, RSQRT_H, ss) : -1e9f;
    }
    __syncthreads();

    {
        int wv = tid >> 6, l = tid & 63;
        for (int r = wv; r < 6; r += 4) {
            float v = (l < NN) ? s.lgL[r][l] : -3.4e38f;
            #pragma unroll
            for (int o = 32; o > 0; o >>= 1) v = fmaxf(v, __shfl_xor(v, o));
            float e = (l < NN) ? expf(s.lgL[r][l] - v) : 0.f;
            float sm = e;
            #pragma unroll
            for (int o = 32; o > 0; o >>= 1) sm += __shfl_xor(sm, o);
            if (l < NN) s.lgL[r][l] = e / sm;
        }
    }
    __syncthreads();
    if (tid < NN) {
        #pragma unroll
        for (int r = 0; r < 6; ++r) s.pL[tid][r] = s.lgL[r][tid];
        s.pL[tid][6] = 0.f; s.pL[tid][7] = 0.f;
    }
    __syncthreads();

    {
        int half = tid >> 7, c = tid & 127;
        float acc[6] = {0,0,0,0,0,0};
        for (int jj = half*24; jj < half*24 + 24; ++jj) {
            float av = s.aVL[jj][c];
            float4 pA = *(const float4*)&s.pL[jj][0];
            float4 pB = *(const float4*)&s.pL[jj][4];
            acc[0] = fmaf(pA.x, av, acc[0]); acc[1] = fmaf(pA.y, av, acc[1]);
            acc[2] = fmaf(pA.z, av, acc[2]); acc[3] = fmaf(pA.w, av, acc[3]);
            acc[4] = fmaf(pB.x, av, acc[4]); acc[5] = fmaf(pB.y, av, acc[5]);
        }
        #pragma unroll
        for (int r = 0; r < 6; ++r) s.pcL[half][r][c] = acc[r];
    }
    __syncthreads();
    for (int idx = tid; idx < 6*HH; idx += 256) {
        int r = idx >> 7, c = idx & 127;
        int row = (b*NN + n0 + r)*TT + t;
        p.nbr_ctx[(size_t)row*HH + c] = s.pcL[0][r][c] + s.pcL[1][r][c];
    }
}

// ---------------- phase 3: output MLP (4 rows per task) ----------------
__device__ void do_tau(const P& p, STA& s, int r0) {
    int tid = threadIdx.x;
    __syncthreads();
    for (int idx = tid; idx < 384; idx += 256) {
        int r = idx / 96, kq = idx % 96;
        const float* src; int co;
        if (kq < 32)      { src = p.a_emb;   co = kq; }
        else if (kq < 64) { src = p.map_ctx; co = kq - 32; }
        else              { src = p.nbr_ctx; co = kq - 64; }
        float4 v = *(const float4*)(src + (size_t)(r0 + r)*HH + co*4);
        int kb = (kq < 32 ? 0 : (kq < 64 ? HH : 2*HH)) + co*4;
        s.xinT[kb+0][r] = v.x; s.xinT[kb+1][r] = v.y;
        s.xinT[kb+2][r] = v.z; s.xinT[kb+3][r] = v.w;
    }
    __syncthreads();
    {
        int c = tid & 127, h = tid >> 7;
        float acc[4] = {0,0,0,0};
        for (int k = h*192; k < h*192 + 192; ++k) {
            float wv = p.to_w0[k*HH + c];
            float4 xa = *(const float4*)&s.xinT[k][0];
            acc[0]=fmaf(xa.x,wv,acc[0]); acc[1]=fmaf(xa.y,wv,acc[1]);
            acc[2]=fmaf(xa.z,wv,acc[2]); acc[3]=fmaf(xa.w,wv,acc[3]);
        }
        #pragma unroll
        for (int r = 0; r < 4; ++r) s.p1L[h][r][c] = acc[r];
    }
    __syncthreads();
    for (int idx = tid; idx < 4*HH; idx += 256) {
        int r = idx >> 7, k = idx & 127;
        s.h1T[k][r] = fmaxf(s.p1L[0][r][k] + s.p1L[1][r][k] + p.to_b0[k], 0.f);
    }
    __syncthreads();
    {
        int r = tid >> 6, c2 = tid & 63;
        float acc = p.to_b1[c2];
        for (int k = 0; k < HH; ++k)
            acc = fmaf(s.h1T[k][r], p.to_w1[k*64 + c2], acc);
        p.tau[(size_t)(r0 + r)*64 + c2] = acc * p.amask[r0 + r];
    }
}

// ---------------- fused persistent kernel ----------------
__global__ __launch_bounds__(256, 2) void k_fused(P p) {
    __shared__ __align__(16) char smraw[sizeof(SNB)];

    // phase 1: map_enc (384 tasks) + agent_enc (576 tasks)
    for (int task = blockIdx.x; task < 960; task += NBLK) {
        if (task < 384) do_map_enc(p, *(SME*)smraw, task);
        else            do_agent_enc(p, *(SAG*)smraw, (task - 384)*4);
    }
    grid_barrier(p.bar, 0, NBLK);

    // phase 2: map_attn (576 tasks) + nbr_attn (384 tasks)
    for (int task = blockIdx.x; task < 960; task += NBLK) {
        if (task < 576) do_map_attn(p, *(SMA*)smraw, task*4);
        else            do_nbr_attn(p, *(SNB*)smraw, task - 576);
    }
    grid_barrier(p.bar, 1, NBLK);

    // phase 3: tau (576 tasks)
    for (int task = blockIdx.x; task < 576; task += NBLK)
        do_tau(p, *(STA*)smraw, task*4);
}

extern "C" void kernel_launch(void* const* d_in, const int* in_sizes, int n_in,
                              void* d_out, int out_size, void* d_ws, size_t ws_size,
                              hipStream_t stream)
{
    P p;
    p.astate    = (const float*)d_in[0];
    p.amask     = (const float*)d_in[1];
    p.polylines = (const float*)d_in[2];
    p.poly_mask = (const float*)d_in[3];
    p.ptype     = (const int*)d_in[4];
    p.tlst      = (const int*)d_in[5];
    p.route     = (const int*)d_in[6];
    p.ae_w0 = (const float*)d_in[7];  p.ae_b0 = (const float*)d_in[8];
    p.ae_w1 = (const float*)d_in[9];  p.ae_b1 = (const float*)d_in[10];
    p.ae_w2 = (const float*)d_in[11]; p.ae_b2 = (const float*)d_in[12];
    p.mp_w0 = (const float*)d_in[13]; p.mp_b0 = (const float*)d_in[14];
    p.mp_w1 = (const float*)d_in[15]; p.mp_b1 = (const float*)d_in[16];
    p.type_emb  = (const float*)d_in[17];
    p.tl_emb    = (const float*)d_in[18];
    p.route_emb = (const float*)d_in[19];
    p.mo_w0 = (const float*)d_in[20]; p.mo_b0 = (const float*)d_in[21];
    p.mo_w1 = (const float*)d_in[22]; p.mo_b1 = (const float*)d_in[23];
    p.mr_w0 = (const float*)d_in[24]; p.mr_b0 = (const float*)d_in[25];
    p.mr_w1 = (const float*)d_in[26]; p.mr_b1 = (const float*)d_in[27];
    p.nr_w0 = (const float*)d_in[28]; p.nr_b0 = (const float*)d_in[29];
    p.nr_w1 = (const float*)d_in[30]; p.nr_b1 = (const float*)d_in[31];
    p.to_w0 = (const float*)d_in[32]; p.to_b0 = (const float*)d_in[33];
    p.to_w1 = (const float*)d_in[34]; p.to_b1 = (const float*)d_in[35];

    p.tau     = (float*)d_out;
    p.map_ctx = (float*)d_out + (size_t)NT*64;
    p.nbr_ctx = p.map_ctx + (size_t)NT*HH;

    p.bar = (unsigned*)d_ws;                                // 256 B barrier area
    float* base   = (float*)((char*)d_ws + 256);
    p.a_emb      = base;                                    // NT*HH
    p.map_node   = p.a_emb + (size_t)NT*HH;                 // B*M*HH
    p.map_nodeT  = p.map_node + (size_t)BB*MM*HH;           // B*HH*MM
    p.map_center = p.map_nodeT + (size_t)BB*MM*HH;          // B*M*2

    hipMemsetAsync(d_ws, 0, 256, stream);                   // zero barrier slots
    k_fused<<<NBLK, 256, 0, stream>>>(p);
}

// Round 6
// 184.434 us; speedup vs baseline: 3.2757x; 3.2757x over previous
//
#include <hip/hip_runtime.h>
#include <math.h>

#define HH 128
#define BB 2
#define NN 48
#define TT 24
#define MM 192
#define LL 20
#define NT (BB*NN*TT)   /* 2304 */
#define RSQRT_H 0.08838834764831845f  /* 1/sqrt(128) */
#define RADIUS_C 30.0f

struct P {
    const float *astate, *amask, *polylines, *poly_mask;
    const int *ptype, *tlst, *route;
    const float *ae_w0,*ae_b0,*ae_w1,*ae_b1,*ae_w2,*ae_b2;
    const float *mp_w0,*mp_b0,*mp_w1,*mp_b1;
    const float *type_emb,*tl_emb,*route_emb;
    const float *mo_w0,*mo_b0,*mo_w1,*mo_b1;
    const float *mr_w0,*mr_b0,*mr_w1,*mr_b1;
    const float *nr_w0,*nr_b0,*nr_w1,*nr_b1;
    const float *to_w0,*to_b0,*to_w1,*to_b1;
    float *tau,*map_ctx,*nbr_ctx;
    float *a_emb,*map_node,*map_nodeT,*map_center;
};

// ---- per-phase LDS layouts (float4 members for conflict-free b128 access) ----
struct SME { float pts[LL*2]; float h1[LL][HH]; float mx[2][HH]; float hb[HH]; float pr[2][HH]; float hb2[HH]; };
struct SAG { float xin[4][5]; float h1[4][HH]; float h2[4][HH]; float p1[2][4][HH]; };
struct SMA { float mnL[16][MM]; float4 w4L[HH]; float w1L[HH]; float4 aq4L[HH]; float lg[4][MM]; float4 p4L[MM]; float invL[4]; float pc[2][4][HH]; };
struct SNB { float aVL[NN][129]; float pjL[NN][8]; float4 wAL[HH]; float4 wBL[HH]; float aqL[HH][8]; float sPL[4][6][NN]; float dPL[4][6][NN]; float lgL[6][NN]; float pL[NN][8]; float pcL[2][6][HH]; };
struct STA { float xinT[3*HH][4]; float p1L[2][4][HH]; float h1T[HH][4]; };

// ---------------- 1a: map polyline encoder (one bm per block, 256 thr) ----------------
__device__ void do_map_enc(const P& p, SME& s, int bm) {
    int tid = threadIdx.x, pp = tid >> 7, c = tid & 127;
    if (tid < LL*2) s.pts[tid] = p.polylines[(size_t)bm*LL*2 + tid];
    __syncthreads();
    {
        float w0x = p.mp_w0[c], w0y = p.mp_w0[HH + c], b0 = p.mp_b0[c];
        #pragma unroll
        for (int i = 0; i < 10; ++i) {
            int pt_ = pp + 2*i;
            s.h1[pt_][c] = fmaxf(fmaf(s.pts[2*pt_], w0x, fmaf(s.pts[2*pt_+1], w0y, b0)), 0.f);
        }
    }
    if (tid < 2) {
        float sum = 0.f;
        for (int q = 0; q < LL; ++q) sum += s.pts[2*q + tid];
        p.map_center[bm*2 + tid] = sum * (1.0f / LL);
    }
    __syncthreads();
    {
        float acc[10];
        float b1 = p.mp_b1[c];
        #pragma unroll
        for (int i = 0; i < 10; ++i) acc[i] = b1;
        for (int k = 0; k < HH; ++k) {
            float wv = p.mp_w1[k*HH + c];
            #pragma unroll
            for (int i = 0; i < 10; ++i) acc[i] = fmaf(s.h1[pp + 2*i][k], wv, acc[i]);
        }
        float m10 = acc[0];
        #pragma unroll
        for (int i = 1; i < 10; ++i) m10 = fmaxf(m10, acc[i]);
        s.mx[pp][c] = m10;
    }
    __syncthreads();
    if (tid < HH) {
        float hm = fmaxf(fmaxf(s.mx[0][c], s.mx[1][c]), 0.f);
        int pt = p.ptype[bm]; pt = pt < 0 ? 0 : (pt > 3 ? 3 : pt);
        int tv = p.tlst[bm];  tv = tv < 0 ? 0 : (tv > 7 ? 7 : tv);
        int rv = p.route[bm]; rv = rv < 0 ? 0 : (rv > 1 ? 1 : rv);
        hm += p.type_emb[pt*HH + c] + p.tl_emb[tv*HH + c] + p.route_emb[rv*HH + c];
        s.hb[c] = hm;
    }
    __syncthreads();
    {
        float sum = 0.f;
        int k0 = pp*64;
        for (int k = k0; k < k0 + 64; ++k) sum = fmaf(s.hb[k], p.mo_w0[k*HH + c], sum);
        s.pr[pp][c] = sum;
    }
    __syncthreads();
    if (tid < HH) s.hb2[c] = fmaxf(s.pr[0][c] + s.pr[1][c] + p.mo_b0[c], 0.f);
    __syncthreads();
    {
        float sum = 0.f;
        int k0 = pp*64;
        for (int k = k0; k < k0 + 64; ++k) sum = fmaf(s.hb2[k], p.mo_w1[k*HH + c], sum);
        s.pr[pp][c] = sum;
    }
    __syncthreads();
    if (tid < HH) {
        float a3 = s.pr[0][c] + s.pr[1][c] + p.mo_b1[c];
        float mk = (p.poly_mask[bm] > 0.5f) ? 1.f : 0.f;
        float v = a3 * mk;
        p.map_node[(size_t)bm*HH + c] = v;
        int b = bm / MM, m = bm % MM;
        p.map_nodeT[((size_t)b*HH + c)*MM + m] = v;
    }
}

// ---------------- 1b: agent encoder (4 rows per block, 256 thr) ----------------
__device__ void do_agent_enc(const P& p, SAG& s, int r0) {
    int tid = threadIdx.x, h = tid >> 7, c = tid & 127;
    if (tid < 20) s.xin[tid/5][tid%5] = p.astate[(size_t)r0*5 + tid];
    __syncthreads();
    if (h == 0) {
        float b = p.ae_b0[c];
        float w[5];
        #pragma unroll
        for (int i = 0; i < 5; ++i) w[i] = p.ae_w0[i*HH + c];
        #pragma unroll
        for (int r = 0; r < 4; ++r) {
            float v = b;
            #pragma unroll
            for (int i = 0; i < 5; ++i) v = fmaf(s.xin[r][i], w[i], v);
            s.h1[r][c] = fmaxf(v, 0.f);
        }
    }
    __syncthreads();
    {
        float acc[4] = {0.f,0.f,0.f,0.f};
        int k0 = h*64;
        for (int k = k0; k < k0 + 64; ++k) {
            float wv = p.ae_w1[k*HH + c];
            #pragma unroll
            for (int r = 0; r < 4; ++r) acc[r] = fmaf(s.h1[r][k], wv, acc[r]);
        }
        #pragma unroll
        for (int r = 0; r < 4; ++r) s.p1[h][r][c] = acc[r];
    }
    __syncthreads();
    {
        #pragma unroll
        for (int rr = 0; rr < 2; ++rr) {
            int r = h*2 + rr;
            s.h2[r][c] = fmaxf(s.p1[0][r][c] + s.p1[1][r][c] + p.ae_b1[c], 0.f);
        }
    }
    __syncthreads();
    {
        float acc[4] = {0.f,0.f,0.f,0.f};
        int k0 = h*64;
        for (int k = k0; k < k0 + 64; ++k) {
            float wv = p.ae_w2[k*HH + c];
            #pragma unroll
            for (int r = 0; r < 4; ++r) acc[r] = fmaf(s.h2[r][k], wv, acc[r]);
        }
        #pragma unroll
        for (int r = 0; r < 4; ++r) s.p1[h][r][c] = acc[r];
    }
    __syncthreads();
    {
        #pragma unroll
        for (int rr = 0; rr < 2; ++rr) {
            int r = h*2 + rr;
            int row = r0 + r;
            p.a_emb[(size_t)row*HH + c] = (s.p1[0][r][c] + s.p1[1][r][c] + p.ae_b2[c]) * p.amask[row];
        }
    }
}

// ---------------- 2a: map cross-attention (4 rows per block, 256 thr) ----------------
__device__ void do_map_attn(const P& p, SMA& s, int bnt0) {
    int b   = bnt0 / (NN*TT);
    int tid = threadIdx.x;

    if (tid < HH) {
        int k = tid;
        s.w4L[k] = make_float4(p.mr_w0[k], p.mr_w0[HH+k], p.mr_w0[2*HH+k], p.mr_b0[k]);
        s.w1L[k] = p.mr_w1[k];
    }
    for (int idx = tid; idx < 4*HH; idx += 256) {
        int r = idx >> 7, k = idx & 127;
        ((float*)&s.aq4L[k])[r] = p.a_emb[(size_t)(bnt0 + r)*HH + k];
    }

    float rx[4], ry[4], rd[4];
    if (tid < MM) {
        float mcx = p.map_center[(b*MM + tid)*2];
        float mcy = p.map_center[(b*MM + tid)*2 + 1];
        #pragma unroll
        for (int r = 0; r < 4; ++r) {
            float px = p.astate[(size_t)(bnt0 + r)*5];
            float py = p.astate[(size_t)(bnt0 + r)*5 + 1];
            rx[r] = mcx - px; ry[r] = mcy - py;
            rd[r] = sqrtf(rx[r]*rx[r] + ry[r]*ry[r]);
        }
    }

    const float* mnT = p.map_nodeT + (size_t)b*HH*MM;
    float4 st[3];
    #pragma unroll
    for (int i = 0; i < 3; ++i) {
        int q = tid + 256*i;
        int kk = q / 48, mq = q % 48;
        st[i] = *(const float4*)(mnT + (size_t)kk*MM + mq*4);
    }
    float sacc[4] = {0.f,0.f,0.f,0.f};
    float dt[4]   = {0.f,0.f,0.f,0.f};
    for (int ch = 0; ch < 8; ++ch) {
        __syncthreads();
        #pragma unroll
        for (int i = 0; i < 3; ++i) {
            int q = tid + 256*i;
            int kk = q / 48, mq = q % 48;
            *(float4*)&s.mnL[kk][mq*4] = st[i];
        }
        __syncthreads();
        if (ch < 7) {
            #pragma unroll
            for (int i = 0; i < 3; ++i) {
                int q = tid + 256*i;
                int kk = q / 48, mq = q % 48;
                st[i] = *(const float4*)(mnT + (size_t)(ch+1)*16*MM + (size_t)kk*MM + mq*4);
            }
        }
        if (tid < MM) {
            int k0 = ch*16;
            #pragma unroll
            for (int kk = 0; kk < 16; ++kk) {
                int k = k0 + kk;
                float4 w  = s.w4L[k];
                float  w1 = s.w1L[k];
                float4 aq = s.aq4L[k];
                float  mn = s.mnL[kk][tid];
                #pragma unroll
                for (int r = 0; r < 4; ++r) {
                    float hv = fmaf(rx[r], w.x, fmaf(ry[r], w.y, fmaf(rd[r], w.z, w.w)));
                    sacc[r] = fmaf(fmaxf(hv, 0.f), w1, sacc[r]);
                }
                dt[0] = fmaf(aq.x, mn, dt[0]);
                dt[1] = fmaf(aq.y, mn, dt[1]);
                dt[2] = fmaf(aq.z, mn, dt[2]);
                dt[3] = fmaf(aq.w, mn, dt[3]);
            }
        }
    }

    if (tid < MM) {
        float pm = p.poly_mask[b*MM + tid];
        float b1 = p.mr_b1[0];
        #pragma unroll
        for (int r = 0; r < 4; ++r) {
            float lgt = fmaf(dt[r], RSQRT_H, sacc[r] + b1);
            s.lg[r][tid] = (pm > 0.5f) ? lgt : -1e9f;
        }
    }
    __syncthreads();

    {
        int r = tid >> 6, l = tid & 63;
        float v = fmaxf(fmaxf(s.lg[r][l], s.lg[r][l+64]), s.lg[r][l+128]);
        #pragma unroll
        for (int o = 32; o > 0; o >>= 1) v = fmaxf(v, __shfl_xor(v, o));
        float e0 = expf(s.lg[r][l] - v);
        float e1 = expf(s.lg[r][l+64] - v);
        float e2 = expf(s.lg[r][l+128] - v);
        s.lg[r][l] = e0; s.lg[r][l+64] = e1; s.lg[r][l+128] = e2;
        float sm = e0 + e1 + e2;
        #pragma unroll
        for (int o = 32; o > 0; o >>= 1) sm += __shfl_xor(sm, o);
        if (l == 0) s.invL[r] = 1.0f / sm;
    }
    __syncthreads();
    if (tid < MM) {
        s.p4L[tid] = make_float4(s.lg[0][tid]*s.invL[0], s.lg[1][tid]*s.invL[1],
                                 s.lg[2][tid]*s.invL[2], s.lg[3][tid]*s.invL[3]);
    }
    __syncthreads();

    {
        int half = tid >> 7, c = tid & 127;
        float a0=0.f, a1=0.f, a2=0.f, a3=0.f;
        const float* mnb = p.map_node + ((size_t)b*MM + half*96)*HH + c;
        for (int m = 0; m < 96; ++m) {
            float mv = mnb[(size_t)m*HH];
            float4 pp4 = s.p4L[half*96 + m];
            a0 = fmaf(pp4.x, mv, a0); a1 = fmaf(pp4.y, mv, a1);
            a2 = fmaf(pp4.z, mv, a2); a3 = fmaf(pp4.w, mv, a3);
        }
        s.pc[half][0][c]=a0; s.pc[half][1][c]=a1; s.pc[half][2][c]=a2; s.pc[half][3][c]=a3;
    }
    __syncthreads();
    for (int idx = tid; idx < 4*HH; idx += 256) {
        int r = idx >> 7, c = idx & 127;
        p.map_ctx[(size_t)(bnt0 + r)*HH + c] = s.pc[0][r][c] + s.pc[1][r][c];
    }
}

// ---------------- 2b: neighbor attention (6 n-rows per block, 256 thr) ----------------
__device__ void do_nbr_attn(const P& p, SNB& s, int task) {
    int b   = task / (TT*8);
    int rem = task % (TT*8);
    int t   = rem / 8;
    int n0  = (rem % 8) * 6;
    int tid = threadIdx.x;

    if (tid < NN) {
        int rj = (b*NN + tid)*TT + t;
        s.pjL[tid][0] = p.astate[(size_t)rj*5];
        s.pjL[tid][1] = p.astate[(size_t)rj*5 + 1];
        s.pjL[tid][2] = p.astate[(size_t)rj*5 + 3];
        s.pjL[tid][3] = p.astate[(size_t)rj*5 + 4];
        s.pjL[tid][4] = p.amask[rj];
    }
    if (tid < HH) {
        int k = tid;
        s.wAL[k] = make_float4(p.nr_w0[k], p.nr_w0[HH+k], p.nr_w0[2*HH+k], p.nr_w0[3*HH+k]);
        s.wBL[k] = make_float4(p.nr_w0[4*HH+k], p.nr_b0[k], p.nr_w1[k], 0.f);
    }
    #pragma unroll
    for (int i = 0; i < 6; ++i) {
        int q = tid + 256*i;
        int j = q >> 5, cq = q & 31;
        float4 v = *(const float4*)(p.a_emb + ((size_t)(b*NN + j)*TT + t)*HH + cq*4);
        s.aVL[j][cq*4+0] = v.x; s.aVL[j][cq*4+1] = v.y;
        s.aVL[j][cq*4+2] = v.z; s.aVL[j][cq*4+3] = v.w;
    }
    __syncthreads();
    for (int idx = tid; idx < 6*HH; idx += 256) {
        int r = idx >> 7, k = idx & 127;
        s.aqL[k][r] = s.aVL[n0 + r][k];
    }
    __syncthreads();

    {
        int j  = tid % 48;
        int kg = tid / 48;
        if (kg < 4) {
            float jx = s.pjL[j][0], jy = s.pjL[j][1], jvx = s.pjL[j][2], jvy = s.pjL[j][3];
            float dx[6], dy[6], dvx[6], dvy[6], dd[6];
            #pragma unroll
            for (int r = 0; r < 6; ++r) {
                dx[r]  = s.pjL[n0+r][0] - jx;  dy[r]  = s.pjL[n0+r][1] - jy;
                dvx[r] = s.pjL[n0+r][2] - jvx; dvy[r] = s.pjL[n0+r][3] - jvy;
                dd[r]  = sqrtf(dx[r]*dx[r] + dy[r]*dy[r]);
            }
            float sr[6]  = {0,0,0,0,0,0};
            float dt[6] = {0,0,0,0,0,0};
            int k0 = kg*32;
            for (int kk = 0; kk < 32; ++kk) {
                int k = k0 + kk;
                float4 wa = s.wAL[k], wb = s.wBL[k];
                float4 aA = *(const float4*)&s.aqL[k][0];
                float4 aB = *(const float4*)&s.aqL[k][4];
                float  av = s.aVL[j][k];
                #pragma unroll
                for (int r = 0; r < 6; ++r) {
                    float hv = fmaf(dx[r], wa.x, fmaf(dy[r], wa.y,
                               fmaf(dvx[r], wa.z, fmaf(dvy[r], wa.w,
                               fmaf(dd[r], wb.x, wb.y)))));
                    sr[r] = fmaf(fmaxf(hv, 0.f), wb.z, sr[r]);
                }
                dt[0] = fmaf(aA.x, av, dt[0]); dt[1] = fmaf(aA.y, av, dt[1]);
                dt[2] = fmaf(aA.z, av, dt[2]); dt[3] = fmaf(aA.w, av, dt[3]);
                dt[4] = fmaf(aB.x, av, dt[4]); dt[5] = fmaf(aB.y, av, dt[5]);
            }
            #pragma unroll
            for (int r = 0; r < 6; ++r) { s.sPL[kg][r][j] = sr[r]; s.dPL[kg][r][j] = dt[r]; }
        }
    }
    __syncthreads();

    float b1 = p.nr_b1[0];
    for (int idx = tid; idx < 6*NN; idx += 256) {
        int r = idx / NN, jj = idx % NN;
        int ni = n0 + r;
        float ss  = s.sPL[0][r][jj] + s.sPL[1][r][jj] + s.sPL[2][r][jj] + s.sPL[3][r][jj] + b1;
        float do2 = s.dPL[0][r][jj] + s.dPL[1][r][jj] + s.dPL[2][r][jj] + s.dPL[3][r][jj];
        float ddx = s.pjL[ni][0] - s.pjL[jj][0];
        float ddy = s.pjL[ni][1] - s.pjL[jj][1];
        float dist = sqrtf(ddx*ddx + ddy*ddy);
        bool ok = (s.pjL[ni][4] > 0.5f) && (s.pjL[jj][4] > 0.5f) &&
                  (dist <= RADIUS_C) && (jj != ni);
        s.lgL[r][jj] = ok ? fmaf(do2, RSQRT_H, ss) : -1e9f;
    }
    __syncthreads();

    {
        int wv = tid >> 6, l = tid & 63;
        for (int r = wv; r < 6; r += 4) {
            float v = (l < NN) ? s.lgL[r][l] : -3.4e38f;
            #pragma unroll
            for (int o = 32; o > 0; o >>= 1) v = fmaxf(v, __shfl_xor(v, o));
            float e = (l < NN) ? expf(s.lgL[r][l] - v) : 0.f;
            float sm = e;
            #pragma unroll
            for (int o = 32; o > 0; o >>= 1) sm += __shfl_xor(sm, o);
            if (l < NN) s.lgL[r][l] = e / sm;
        }
    }
    __syncthreads();
    if (tid < NN) {
        #pragma unroll
        for (int r = 0; r < 6; ++r) s.pL[tid][r] = s.lgL[r][tid];
        s.pL[tid][6] = 0.f; s.pL[tid][7] = 0.f;
    }
    __syncthreads();

    {
        int half = tid >> 7, c = tid & 127;
        float acc[6] = {0,0,0,0,0,0};
        for (int jj = half*24; jj < half*24 + 24; ++jj) {
            float av = s.aVL[jj][c];
            float4 pA = *(const float4*)&s.pL[jj][0];
            float4 pB = *(const float4*)&s.pL[jj][4];
            acc[0] = fmaf(pA.x, av, acc[0]); acc[1] = fmaf(pA.y, av, acc[1]);
            acc[2] = fmaf(pA.z, av, acc[2]); acc[3] = fmaf(pA.w, av, acc[3]);
            acc[4] = fmaf(pB.x, av, acc[4]); acc[5] = fmaf(pB.y, av, acc[5]);
        }
        #pragma unroll
        for (int r = 0; r < 6; ++r) s.pcL[half][r][c] = acc[r];
    }
    __syncthreads();
    for (int idx = tid; idx < 6*HH; idx += 256) {
        int r = idx >> 7, c = idx & 127;
        int row = (b*NN + n0 + r)*TT + t;
        p.nbr_ctx[(size_t)row*HH + c] = s.pcL[0][r][c] + s.pcL[1][r][c];
    }
}

// ---------------- kernel A: encoders (960 blocks) ----------------
__global__ __launch_bounds__(256) void k_enc(P p) {
    __shared__ __align__(16) char smraw[(sizeof(SME) > sizeof(SAG)) ? sizeof(SME) : sizeof(SAG)];
    int task = blockIdx.x;
    if (task < BB*MM) do_map_enc(p, *(SME*)smraw, task);
    else              do_agent_enc(p, *(SAG*)smraw, (task - BB*MM)*4);
}

// ---------------- kernel B: attentions (960 blocks) ----------------
__global__ __launch_bounds__(256) void k_attn(P p) {
    __shared__ __align__(16) char smraw[(sizeof(SMA) > sizeof(SNB)) ? sizeof(SMA) : sizeof(SNB)];
    int task = blockIdx.x;
    if (task < NT/4) do_map_attn(p, *(SMA*)smraw, task*4);
    else             do_nbr_attn(p, *(SNB*)smraw, task - NT/4);
}

// ---------------- kernel C: output MLP (576 blocks, 4 rows each) ----------------
__global__ __launch_bounds__(256) void k_tau(P p) {
    __shared__ __align__(16) STA s;
    int r0  = blockIdx.x * 4;
    int tid = threadIdx.x;
    for (int idx = tid; idx < 384; idx += 256) {
        int r = idx / 96, kq = idx % 96;
        const float* src; int co;
        if (kq < 32)      { src = p.a_emb;   co = kq; }
        else if (kq < 64) { src = p.map_ctx; co = kq - 32; }
        else              { src = p.nbr_ctx; co = kq - 64; }
        float4 v = *(const float4*)(src + (size_t)(r0 + r)*HH + co*4);
        int kb = (kq < 32 ? 0 : (kq < 64 ? HH : 2*HH)) + co*4;
        s.xinT[kb+0][r] = v.x; s.xinT[kb+1][r] = v.y;
        s.xinT[kb+2][r] = v.z; s.xinT[kb+3][r] = v.w;
    }
    __syncthreads();
    {
        int c = tid & 127, h = tid >> 7;
        float acc[4] = {0,0,0,0};
        for (int k = h*192; k < h*192 + 192; ++k) {
            float wv = p.to_w0[k*HH + c];
            float4 xa = *(const float4*)&s.xinT[k][0];
            acc[0]=fmaf(xa.x,wv,acc[0]); acc[1]=fmaf(xa.y,wv,acc[1]);
            acc[2]=fmaf(xa.z,wv,acc[2]); acc[3]=fmaf(xa.w,wv,acc[3]);
        }
        #pragma unroll
        for (int r = 0; r < 4; ++r) s.p1L[h][r][c] = acc[r];
    }
    __syncthreads();
    for (int idx = tid; idx < 4*HH; idx += 256) {
        int r = idx >> 7, k = idx & 127;
        s.h1T[k][r] = fmaxf(s.p1L[0][r][k] + s.p1L[1][r][k] + p.to_b0[k], 0.f);
    }
    __syncthreads();
    {
        int r = tid >> 6, c2 = tid & 63;
        float acc = p.to_b1[c2];
        for (int k = 0; k < HH; ++k)
            acc = fmaf(s.h1T[k][r], p.to_w1[k*64 + c2], acc);
        p.tau[(size_t)(r0 + r)*64 + c2] = acc * p.amask[r0 + r];
    }
}

extern "C" void kernel_launch(void* const* d_in, const int* in_sizes, int n_in,
                              void* d_out, int out_size, void* d_ws, size_t ws_size,
                              hipStream_t stream)
{
    P p;
    p.astate    = (const float*)d_in[0];
    p.amask     = (const float*)d_in[1];
    p.polylines = (const float*)d_in[2];
    p.poly_mask = (const float*)d_in[3];
    p.ptype     = (const int*)d_in[4];
    p.tlst      = (const int*)d_in[5];
    p.route     = (const int*)d_in[6];
    p.ae_w0 = (const float*)d_in[7];  p.ae_b0 = (const float*)d_in[8];
    p.ae_w1 = (const float*)d_in[9];  p.ae_b1 = (const float*)d_in[10];
    p.ae_w2 = (const float*)d_in[11]; p.ae_b2 = (const float*)d_in[12];
    p.mp_w0 = (const float*)d_in[13]; p.mp_b0 = (const float*)d_in[14];
    p.mp_w1 = (const float*)d_in[15]; p.mp_b1 = (const float*)d_in[16];
    p.type_emb  = (const float*)d_in[17];
    p.tl_emb    = (const float*)d_in[18];
    p.route_emb = (const float*)d_in[19];
    p.mo_w0 = (const float*)d_in[20]; p.mo_b0 = (const float*)d_in[21];
    p.mo_w1 = (const float*)d_in[22]; p.mo_b1 = (const float*)d_in[23];
    p.mr_w0 = (const float*)d_in[24]; p.mr_b0 = (const float*)d_in[25];
    p.mr_w1 = (const float*)d_in[26]; p.mr_b1 = (const float*)d_in[27];
    p.nr_w0 = (const float*)d_in[28]; p.nr_b0 = (const float*)d_in[29];
    p.nr_w1 = (const float*)d_in[30]; p.nr_b1 = (const float*)d_in[31];
    p.to_w0 = (const float*)d_in[32]; p.to_b0 = (const float*)d_in[33];
    p.to_w1 = (const float*)d_in[34]; p.to_b1 = (const float*)d_in[35];

    p.tau     = (float*)d_out;
    p.map_ctx = (float*)d_out + (size_t)NT*64;
    p.nbr_ctx = p.map_ctx + (size_t)NT*HH;

    float* ws    = (float*)d_ws;
    p.a_emb      = ws;                                   // NT*HH
    p.map_node   = p.a_emb + (size_t)NT*HH;              // B*M*HH
    p.map_nodeT  = p.map_node + (size_t)BB*MM*HH;        // B*HH*MM
    p.map_center = p.map_nodeT + (size_t)BB*MM*HH;       // B*M*2

    k_enc <<<BB*MM + NT/4,        256, 0, stream>>>(p);   // 384 + 576 = 960
    k_attn<<<NT/4 + BB*TT*8,      256, 0, stream>>>(p);   // 576 + 384 = 960
    k_tau <<<NT/4,                256, 0, stream>>>(p);   // 576
}